// Round 1
// baseline (1017.436 us; speedup 1.0000x reference)
//
#include <hip/hip_runtime.h>

// Sparse-conv encoder. Strategy: invert each kernel-map (k-offset -> unique out
// rows) into a dense gather table tab[k][j] = in_idx (pad = n_in), then each
// conv is one thread per output row, gathering input rows and FMA-ing against
// wave-uniform weights (compiler emits s_load + v_fmac w/ SGPR operand).

#define TPB 256

__global__ void fill_i32(int* __restrict__ p, long long n, int val) {
    long long i = (long long)blockIdx.x * blockDim.x + threadIdx.x;
    if (i < n) p[i] = val;
}

__global__ void scatter_tab(const int* __restrict__ km_in,
                            const int* __restrict__ km_out,
                            int* __restrict__ tab, long long rowlen, long long P,
                            long long total) {
    long long t = (long long)blockIdx.x * blockDim.x + threadIdx.x;
    if (t >= total) return;
    long long k = t / P;
    int o = km_out[t];           // pad -> n_out (== rowlen-1), harmless slot
    tab[k * rowlen + o] = km_in[t];
}

// first conv: C_IN=1 -> C0=16, K=27, relu, writes cached region of d_out
__global__ __launch_bounds__(TPB) void conv_first_k(
    const float* __restrict__ xin, const float* __restrict__ W, // (27,1,16)
    const float* __restrict__ b, const int* __restrict__ tab,
    int n0, float* __restrict__ out) {
    int j = blockIdx.x * blockDim.x + threadIdx.x;
    if (j >= n0) return;
    float acc[16];
#pragma unroll
    for (int c = 0; c < 16; ++c) acc[c] = b[c];
    const long long row = (long long)n0 + 1;
    for (int k = 0; k < 27; ++k) {
        int idx = tab[(long long)k * row + j];
        if (idx < n0) {
            float v = xin[idx];
            const float* Wk = W + k * 16;
#pragma unroll
            for (int c = 0; c < 16; ++c) acc[c] = fmaf(v, Wk[c], acc[c]);
        }
    }
#pragma unroll
    for (int c = 0; c < 16; ++c) acc[c] = fmaxf(acc[c], 0.f);
    float* orow = out + (long long)j * 16;
#pragma unroll
    for (int c4 = 0; c4 < 4; ++c4)
        ((float4*)orow)[c4] = make_float4(acc[4*c4], acc[4*c4+1], acc[4*c4+2], acc[4*c4+3]);
}

template <int CIN, int COUT, int K, bool RELU, bool RES>
__global__ __launch_bounds__(TPB) void conv_k(
    const float* __restrict__ x, const float* __restrict__ W, // (K,CIN,COUT)
    const float* __restrict__ b, const int* __restrict__ tab,
    int n_in, int n_out, const float* __restrict__ res,
    float* __restrict__ out) {
    int j = blockIdx.x * blockDim.x + threadIdx.x;
    if (j >= n_out) return;
    float acc[COUT];
#pragma unroll
    for (int c = 0; c < COUT; ++c) acc[c] = b[c];
    const long long row = (long long)n_out + 1;
    for (int k = 0; k < K; ++k) {
        int idx = tab[(long long)k * row + j];
        if (idx < n_in) {
            const float4* xr = (const float4*)(x + (long long)idx * CIN);
            const float* Wk = W + (long long)k * CIN * COUT;
#pragma unroll
            for (int c4 = 0; c4 < CIN / 4; ++c4) {
                float4 xv = xr[c4];
#pragma unroll
                for (int u = 0; u < 4; ++u) {
                    float xs = (u == 0) ? xv.x : (u == 1) ? xv.y : (u == 2) ? xv.z : xv.w;
                    const float* wrow = Wk + (c4 * 4 + u) * COUT;
#pragma unroll
                    for (int c = 0; c < COUT; ++c)
                        acc[c] = fmaf(xs, wrow[c], acc[c]);
                }
            }
        }
    }
    if (RES) {
        const float* rrow = res + (long long)j * COUT;
#pragma unroll
        for (int c = 0; c < COUT; ++c) acc[c] += rrow[c];
    }
    if (RELU) {
#pragma unroll
        for (int c = 0; c < COUT; ++c) acc[c] = fmaxf(acc[c], 0.f);
    }
    float* orow = out + (long long)j * COUT;
#pragma unroll
    for (int c4 = 0; c4 < COUT / 4; ++c4)
        ((float4*)orow)[c4] = make_float4(acc[4*c4], acc[4*c4+1], acc[4*c4+2], acc[4*c4+3]);
}

static inline unsigned nblk(long long n, int b) { return (unsigned)((n + b - 1) / b); }

extern "C" void kernel_launch(void* const* d_in, const int* in_sizes, int n_in_cnt,
                              void* d_out, int out_size, void* d_ws, size_t ws_size,
                              hipStream_t stream) {
    const float* in_feats = (const float*)d_in[0];
    const float* W_first = (const float*)d_in[1];
    const float* b_first = (const float*)d_in[2];
    const float* W_pre   = (const float*)d_in[3];
    const float* b_pre   = (const float*)d_in[4];
    const float* W_down  = (const float*)d_in[5];
    const float* b_down  = (const float*)d_in[6];
    const float* W_r0    = (const float*)d_in[7];
    const float* b_r0    = (const float*)d_in[8];
    const float* W_r1    = (const float*)d_in[9];
    const float* b_r1    = (const float*)d_in[10];
    const float* W_fin   = (const float*)d_in[11];
    const float* b_fin   = (const float*)d_in[12];
    const int* km0_in  = (const int*)d_in[13];
    const int* km0_out = (const int*)d_in[14];
    const int* kmd_in  = (const int*)d_in[15];
    const int* kmd_out = (const int*)d_in[16];
    const int* km1_in  = (const int*)d_in[17];
    const int* km1_out = (const int*)d_in[18];

    const int n0 = in_sizes[0];                    // C_IN == 1
    const int n1 = (out_size - 16 * n0) / 32;      // out = n1*32 + n0*16
    const long long P0 = in_sizes[13] / 27;
    const long long Pd = in_sizes[15] / 8;
    const long long P1 = in_sizes[17] / 27;

    float* out_lo = (float*)d_out;                 // (n1,32)
    float* cached = out_lo + (size_t)n1 * 32;      // (n0,16) — also x0a

    char* ws = (char*)d_ws;
    int* t0 = (int*)ws;      ws += sizeof(int) * 27ll * (n0 + 1);
    int* t1 = (int*)ws;      ws += sizeof(int) * 27ll * (n1 + 1);
    int* td = (int*)ws;      ws += sizeof(int) * 8ll  * (n1 + 1);
    float* x0b = (float*)ws; ws += sizeof(float) * 16ll * n0;
    float* x1a = (float*)ws; ws += sizeof(float) * 32ll * n1;
    float* x1b = (float*)ws; ws += sizeof(float) * 32ll * n1;
    (void)ws_size; (void)n_in_cnt;

    const long long t0n = 27ll * (n0 + 1);
    const long long t1n = 27ll * (n1 + 1);
    const long long tdn = 8ll * (n1 + 1);

    // build inverted gather tables
    fill_i32<<<nblk(t0n, TPB), TPB, 0, stream>>>(t0, t0n, n0);
    fill_i32<<<nblk(t1n, TPB), TPB, 0, stream>>>(t1, t1n, n1);
    fill_i32<<<nblk(tdn, TPB), TPB, 0, stream>>>(td, tdn, n0);
    scatter_tab<<<nblk(27 * P0, TPB), TPB, 0, stream>>>(km0_in, km0_out, t0, n0 + 1, P0, 27 * P0);
    scatter_tab<<<nblk(27 * P1, TPB), TPB, 0, stream>>>(km1_in, km1_out, t1, n1 + 1, P1, 27 * P1);
    scatter_tab<<<nblk(8 * Pd, TPB), TPB, 0, stream>>>(kmd_in, kmd_out, td, n1 + 1, Pd, 8 * Pd);

    // first: 1 -> 16, relu -> cached (region of d_out)
    conv_first_k<<<nblk(n0, TPB), TPB, 0, stream>>>(in_feats, W_first, b_first, t0, n0, cached);
    // pre: 16 -> 16, relu
    conv_k<16, 16, 27, true, false><<<nblk(n0, TPB), TPB, 0, stream>>>(
        cached, W_pre, b_pre, t0, n0, n0, nullptr, x0b);
    // down: 16 -> 32, relu (n0 -> n1)
    conv_k<16, 32, 8, true, false><<<nblk(n1, TPB), TPB, 0, stream>>>(
        x0b, W_down, b_down, td, n0, n1, nullptr, x1a);
    // r0: 32 -> 32, relu
    conv_k<32, 32, 27, true, false><<<nblk(n1, TPB), TPB, 0, stream>>>(
        x1a, W_r0, b_r0, t1, n1, n1, nullptr, x1b);
    // r1: 32 -> 32, + residual x1a, no relu, in-place into x1a
    conv_k<32, 32, 27, false, true><<<nblk(n1, TPB), TPB, 0, stream>>>(
        x1b, W_r1, b_r1, t1, n1, n1, x1a, x1a);
    // fin: 32 -> 32, no relu -> d_out
    conv_k<32, 32, 27, false, false><<<nblk(n1, TPB), TPB, 0, stream>>>(
        x1a, W_fin, b_fin, t1, n1, n1, nullptr, out_lo);
}

// Round 2
// 611.536 us; speedup vs baseline: 1.6637x; 1.6637x over previous
//
#include <hip/hip_runtime.h>

// Sparse-conv encoder, bf16-MFMA implicit-GEMM version.
// Tables are inverted (tab[k][j] = in_idx, pad = n_in -> dedicated zero row in
// the bf16 feature buffer), so each conv is: per wave, 16 output rows x 32
// output channels; per kernel offset, gather A fragments from the bf16 feature
// buffer and multiply against pre-packed bf16 W fragments with
// v_mfma_f32_16x16x32_bf16 (fp32 accumulate). ReLU/bias/residual in epilogue.

#define TPB 256

typedef __attribute__((ext_vector_type(8))) short short8;
typedef __attribute__((ext_vector_type(4))) float floatx4;

static __device__ __forceinline__ unsigned short f2b(float f) {
    union { float f; unsigned u; } v; v.f = f;
    unsigned r = v.u + 0x7fffu + ((v.u >> 16) & 1u);   // RNE
    return (unsigned short)(r >> 16);
}
static __device__ __forceinline__ float b2f(unsigned short h) {
    union { unsigned u; float f; } v; v.u = ((unsigned)h) << 16;
    return v.f;
}

__global__ void fill_i32(int* __restrict__ p, long long n, int val) {
    long long i = (long long)blockIdx.x * blockDim.x + threadIdx.x;
    if (i < n) p[i] = val;
}

__global__ void scatter_tab(const int* __restrict__ km_in,
                            const int* __restrict__ km_out,
                            int* __restrict__ tab, long long rowcap, long long P,
                            long long total) {
    long long t = (long long)blockIdx.x * blockDim.x + threadIdx.x;
    if (t >= total) return;
    long long k = t / P;
    int o = km_out[t];               // pad -> n_out slot (inside rowcap)
    tab[k * rowcap + o] = km_in[t];
}

// zero the pad rows of the 5 bf16 feature buffers (ws is 0xAA-poisoned)
__global__ void zero_pads(unsigned short* a, unsigned short* b, unsigned short* c,
                          unsigned short* d, unsigned short* e) {
    int t = threadIdx.x;             // 160 threads
    if (t < 16) a[t] = 0;
    else if (t < 32) b[t - 16] = 0;
    else if (t < 64) c[t - 32] = 0;
    else if (t < 96) d[t - 64] = 0;
    else if (t < 128) e[t - 96] = 0;
}

// pack W (K,32,COUT=32) f32 -> Wp bf16 at [((k*4+q)*32+n)*8+j] = W[k][q*8+j][n]
__global__ void pack_w32(const float* __restrict__ W, unsigned short* __restrict__ Wp,
                         int K) {
    int t = blockIdx.x * blockDim.x + threadIdx.x;
    if (t >= K * 1024) return;
    int j = t & 7, n = (t >> 3) & 31, q = (t >> 8) & 3, k = t >> 10;
    Wp[t] = f2b(W[(k * 32 + q * 8 + j) * 32 + n]);
}

// pack W (Ksrc,16,COUT) f32 -> Wp bf16; two src offsets per K=32 step:
// Wp[((k2*4+q)*COUT+n)*8+j] = W[2*k2+(q>>1)][(q&1)*8+j][n] (zero past Ksrc)
__global__ void pack_w16(const float* __restrict__ W, unsigned short* __restrict__ Wp,
                         int K2, int COUT, int Ksrc) {
    int t = blockIdx.x * blockDim.x + threadIdx.x;
    if (t >= K2 * 4 * COUT * 8) return;
    int j = t & 7;
    int r = t >> 3;
    int n = r % COUT; r /= COUT;
    int q = r & 3;
    int k2 = r >> 2;
    int ks = 2 * k2 + (q >> 1);
    int cin = (q & 1) * 8 + j;
    float v = (ks < Ksrc) ? W[(ks * 16 + cin) * COUT + n] : 0.f;
    Wp[t] = f2b(v);
}

// first conv: C_IN=1 -> 16, K=27, relu; writes f32 (cached out) + bf16 copy
__global__ __launch_bounds__(TPB) void conv_first_k(
    const float* __restrict__ xin, const float* __restrict__ W,
    const float* __restrict__ b, const int* __restrict__ tab, long long rowcap,
    int n0, float* __restrict__ outf, unsigned short* __restrict__ outb) {
    int j = blockIdx.x * blockDim.x + threadIdx.x;
    if (j >= n0) return;
    float acc[16];
#pragma unroll
    for (int c = 0; c < 16; ++c) acc[c] = b[c];
    for (int k = 0; k < 27; ++k) {
        int idx = tab[(long long)k * rowcap + j];
        if (idx < n0) {
            float v = xin[idx];
            const float* Wk = W + k * 16;
#pragma unroll
            for (int c = 0; c < 16; ++c) acc[c] = fmaf(v, Wk[c], acc[c]);
        }
    }
    float* orow = outf + (long long)j * 16;
    unsigned short* brow = outb + (long long)j * 16;
#pragma unroll
    for (int c = 0; c < 16; ++c) {
        float v = fmaxf(acc[c], 0.f);
        orow[c] = v;
        brow[c] = f2b(v);
    }
}

// MFMA conv. CIN in {16,32}. For CIN=32: one offset per K=32 step (coff=q*8).
// For CIN=16: two offsets per step (ks=2s+(q>>1), coff=(q&1)*8).
template <int CIN, int COUT, int STEPS, bool RELU, bool RES, bool WF32, bool WB16>
__global__ __launch_bounds__(TPB) void conv_mfma(
    const unsigned short* __restrict__ xb,   // (n_in+1, CIN) bf16, pad row zero
    const unsigned short* __restrict__ Wp,   // packed STEPS*4*COUT*8 bf16
    const float* __restrict__ bias,
    const int* __restrict__ tab, long long rowcap, int n_out,
    const unsigned short* __restrict__ resb,
    float* __restrict__ outf, unsigned short* __restrict__ outb) {
    int wid = (blockIdx.x * (int)blockDim.x + (int)threadIdx.x) >> 6;
    int lane = threadIdx.x & 63;
    int m = lane & 15, q = lane >> 4;
    long long j0 = (long long)wid * 16;
    if (j0 >= n_out) return;
    floatx4 acc0 = {0.f, 0.f, 0.f, 0.f};
    floatx4 acc1 = {0.f, 0.f, 0.f, 0.f};
    constexpr bool NT2 = (COUT == 32);
#pragma unroll
    for (int s = 0; s < STEPS; ++s) {
        int ks, coff;
        if (CIN == 32) { ks = s; coff = q * 8; }
        else { ks = 2 * s + (q >> 1); coff = (q & 1) * 8; }
        int idx = tab[(long long)ks * rowcap + j0 + m];
        short8 a = *(const short8*)(xb + (long long)idx * CIN + coff);
        short8 b0 = *(const short8*)(Wp + (((s * 4 + q) * COUT) + m) * 8);
        acc0 = __builtin_amdgcn_mfma_f32_16x16x32_bf16(a, b0, acc0, 0, 0, 0);
        if (NT2) {
            short8 b1 = *(const short8*)(Wp + (((s * 4 + q) * COUT) + 16 + m) * 8);
            acc1 = __builtin_amdgcn_mfma_f32_16x16x32_bf16(a, b1, acc1, 0, 0, 0);
        }
    }
    float bs0 = bias[m];
    float bs1 = NT2 ? bias[16 + m] : 0.f;
#pragma unroll
    for (int t = 0; t < 4; ++t) {
        long long r = j0 + q * 4 + t;   // C/D: row=(lane>>4)*4+reg, col=lane&15
        if (r < n_out) {
            float v0 = acc0[t] + bs0;
            float v1 = NT2 ? (acc1[t] + bs1) : 0.f;
            if (RES) {
                v0 += b2f(resb[r * COUT + m]);
                if (NT2) v1 += b2f(resb[r * COUT + 16 + m]);
            }
            if (RELU) { v0 = fmaxf(v0, 0.f); if (NT2) v1 = fmaxf(v1, 0.f); }
            if (WF32) {
                outf[r * COUT + m] = v0;
                if (NT2) outf[r * COUT + 16 + m] = v1;
            }
            if (WB16) {
                outb[r * COUT + m] = f2b(v0);
                if (NT2) outb[r * COUT + 16 + m] = f2b(v1);
            }
        }
    }
}

static inline unsigned nblk(long long n, int b) { return (unsigned)((n + b - 1) / b); }
static inline size_t align64(size_t x) { return (x + 63) & ~(size_t)63; }

extern "C" void kernel_launch(void* const* d_in, const int* in_sizes, int n_in_cnt,
                              void* d_out, int out_size, void* d_ws, size_t ws_size,
                              hipStream_t stream) {
    const float* in_feats = (const float*)d_in[0];
    const float* W_first = (const float*)d_in[1];
    const float* b_first = (const float*)d_in[2];
    const float* W_pre   = (const float*)d_in[3];
    const float* b_pre   = (const float*)d_in[4];
    const float* W_down  = (const float*)d_in[5];
    const float* b_down  = (const float*)d_in[6];
    const float* W_r0    = (const float*)d_in[7];
    const float* b_r0    = (const float*)d_in[8];
    const float* W_r1    = (const float*)d_in[9];
    const float* b_r1    = (const float*)d_in[10];
    const float* W_fin   = (const float*)d_in[11];
    const float* b_fin   = (const float*)d_in[12];
    const int* km0_in  = (const int*)d_in[13];
    const int* km0_out = (const int*)d_in[14];
    const int* kmd_in  = (const int*)d_in[15];
    const int* kmd_out = (const int*)d_in[16];
    const int* km1_in  = (const int*)d_in[17];
    const int* km1_out = (const int*)d_in[18];

    const int n0 = in_sizes[0];
    const int n1 = (out_size - 16 * n0) / 32;
    const long long P0 = in_sizes[13] / 27;
    const long long Pd = in_sizes[15] / 8;
    const long long P1 = in_sizes[17] / 27;

    const long long rc0 = ((n0 + 16) / 16) * 16;   // covers wave rows + pad slot
    const long long rc1 = ((n1 + 16) / 16) * 16;

    float* out_lo = (float*)d_out;                 // (n1,32)
    float* cached = out_lo + (size_t)n1 * 32;      // (n0,16) f32

    char* base = (char*)d_ws;
    size_t off = 0;
    auto alloc = [&](size_t bytes) { void* p = base + off; off = align64(off + bytes); return p; };
    int* t0 = (int*)alloc(sizeof(int) * 28 * rc0);     // 27 offsets + zero row 27
    int* t1 = (int*)alloc(sizeof(int) * 27 * rc1);
    int* td = (int*)alloc(sizeof(int) * 8 * rc1);
    unsigned short* c0b   = (unsigned short*)alloc(sizeof(short) * 16 * (n0 + 1));
    unsigned short* x0pre = (unsigned short*)alloc(sizeof(short) * 16 * (n0 + 1));
    unsigned short* x1a   = (unsigned short*)alloc(sizeof(short) * 32 * (n1 + 1));
    unsigned short* x1b   = (unsigned short*)alloc(sizeof(short) * 32 * (n1 + 1));
    unsigned short* x1c   = (unsigned short*)alloc(sizeof(short) * 32 * (n1 + 1));
    unsigned short* wp_pre  = (unsigned short*)alloc(sizeof(short) * 14 * 4 * 16 * 8);
    unsigned short* wp_down = (unsigned short*)alloc(sizeof(short) * 4 * 4 * 32 * 8);
    unsigned short* wp_r0   = (unsigned short*)alloc(sizeof(short) * 27 * 1024);
    unsigned short* wp_r1   = (unsigned short*)alloc(sizeof(short) * 27 * 1024);
    unsigned short* wp_fin  = (unsigned short*)alloc(sizeof(short) * 27 * 1024);
    (void)ws_size; (void)n_in_cnt;

    // tables
    fill_i32<<<nblk(28 * rc0, TPB), TPB, 0, stream>>>(t0, 28 * rc0, n0);
    fill_i32<<<nblk(27 * rc1, TPB), TPB, 0, stream>>>(t1, 27 * rc1, n1);
    fill_i32<<<nblk(8 * rc1, TPB), TPB, 0, stream>>>(td, 8 * rc1, n0);
    scatter_tab<<<nblk(27 * P0, TPB), TPB, 0, stream>>>(km0_in, km0_out, t0, rc0, P0, 27 * P0);
    scatter_tab<<<nblk(27 * P1, TPB), TPB, 0, stream>>>(km1_in, km1_out, t1, rc1, P1, 27 * P1);
    scatter_tab<<<nblk(8 * Pd, TPB), TPB, 0, stream>>>(kmd_in, kmd_out, td, rc1, Pd, 8 * Pd);

    // weight packing + pad rows
    pack_w16<<<nblk(14 * 4 * 16 * 8, TPB), TPB, 0, stream>>>(W_pre, wp_pre, 14, 16, 27);
    pack_w16<<<nblk(4 * 4 * 32 * 8, TPB), TPB, 0, stream>>>(W_down, wp_down, 4, 32, 8);
    pack_w32<<<nblk(27 * 1024, TPB), TPB, 0, stream>>>(W_r0, wp_r0, 27);
    pack_w32<<<nblk(27 * 1024, TPB), TPB, 0, stream>>>(W_r1, wp_r1, 27);
    pack_w32<<<nblk(27 * 1024, TPB), TPB, 0, stream>>>(W_fin, wp_fin, 27);
    zero_pads<<<1, 160, 0, stream>>>(c0b + (size_t)n0 * 16, x0pre + (size_t)n0 * 16,
                                     x1a + (size_t)n1 * 32, x1b + (size_t)n1 * 32,
                                     x1c + (size_t)n1 * 32);

    // first: 1 -> 16, relu -> cached (f32) + c0b (bf16)
    conv_first_k<<<nblk(n0, TPB), TPB, 0, stream>>>(in_feats, W_first, b_first, t0, rc0,
                                                    n0, cached, c0b);
    const unsigned waves0 = nblk(n0, 16), waves1 = nblk(n1, 16);
    // pre: 16 -> 16 relu (bf16 out)
    conv_mfma<16, 16, 14, true, false, false, true><<<nblk(waves0 * 64, TPB), TPB, 0, stream>>>(
        c0b, wp_pre, b_pre, t0, rc0, n0, nullptr, nullptr, x0pre);
    // down: 16 -> 32 relu
    conv_mfma<16, 32, 4, true, false, false, true><<<nblk(waves1 * 64, TPB), TPB, 0, stream>>>(
        x0pre, wp_down, b_down, td, rc1, n1, nullptr, nullptr, x1a);
    // r0: 32 -> 32 relu
    conv_mfma<32, 32, 27, true, false, false, true><<<nblk(waves1 * 64, TPB), TPB, 0, stream>>>(
        x1a, wp_r0, b_r0, t1, rc1, n1, nullptr, nullptr, x1b);
    // r1: 32 -> 32 + residual x1a, no relu
    conv_mfma<32, 32, 27, false, true, false, true><<<nblk(waves1 * 64, TPB), TPB, 0, stream>>>(
        x1b, wp_r1, b_r1, t1, rc1, n1, x1a, nullptr, x1c);
    // fin: 32 -> 32 -> d_out (f32)
    conv_mfma<32, 32, 27, false, false, true, false><<<nblk(waves1 * 64, TPB), TPB, 0, stream>>>(
        x1c, wp_fin, b_fin, t1, rc1, n1, nullptr, out_lo, nullptr);
}

// Round 3
// 520.028 us; speedup vs baseline: 1.9565x; 1.1760x over previous
//
#include <hip/hip_runtime.h>

// Sparse-conv encoder, bf16-MFMA implicit-GEMM, M=64 register blocking.
// tab[k][j] = in_idx (pad = n_in -> zero row). Per wave: 64 output rows x
// COUT channels; per offset step: 4 independent idx loads -> 4 independent
// 16B gathers -> 8 (or 4) MFMAs against 2 (or 1) shared B fragments.

#define TPB 256

typedef __attribute__((ext_vector_type(8))) short short8;
typedef __attribute__((ext_vector_type(4))) float floatx4;

static __device__ __forceinline__ unsigned short f2b(float f) {
    union { float f; unsigned u; } v; v.f = f;
    unsigned r = v.u + 0x7fffu + ((v.u >> 16) & 1u);   // RNE
    return (unsigned short)(r >> 16);
}
static __device__ __forceinline__ float b2f(unsigned short h) {
    union { unsigned u; float f; } v; v.u = ((unsigned)h) << 16;
    return v.f;
}

__global__ void fill_i32v(int* __restrict__ p, long long n4, int val) {
    long long i = (long long)blockIdx.x * blockDim.x + threadIdx.x;
    if (i < n4) ((int4*)p)[i] = make_int4(val, val, val, val);
}

__global__ void scatter_tab(const int* __restrict__ km_in,
                            const int* __restrict__ km_out,
                            int* __restrict__ tab, long long rowcap, long long P,
                            long long total) {
    long long t = (long long)blockIdx.x * blockDim.x + threadIdx.x;
    if (t >= total) return;
    long long k = t / P;
    int o = km_out[t];               // pad -> n_out slot (inside rowcap)
    tab[k * rowcap + o] = km_in[t];
}

// zero the pad rows of the 5 bf16 feature buffers (ws is 0xAA-poisoned)
__global__ void zero_pads(unsigned short* a, unsigned short* b, unsigned short* c,
                          unsigned short* d, unsigned short* e) {
    int t = threadIdx.x;             // 160 threads
    if (t < 16) a[t] = 0;
    else if (t < 32) b[t - 16] = 0;
    else if (t < 64) c[t - 32] = 0;
    else if (t < 96) d[t - 64] = 0;
    else if (t < 128) e[t - 96] = 0;
}

// pack W (K,32,COUT=32) f32 -> Wp bf16 at [((k*4+q)*32+n)*8+j] = W[k][q*8+j][n]
__global__ void pack_w32(const float* __restrict__ W, unsigned short* __restrict__ Wp,
                         int K) {
    int t = blockIdx.x * blockDim.x + threadIdx.x;
    if (t >= K * 1024) return;
    int j = t & 7, n = (t >> 3) & 31, q = (t >> 8) & 3, k = t >> 10;
    Wp[t] = f2b(W[(k * 32 + q * 8 + j) * 32 + n]);
}

// pack W (Ksrc,16,COUT) f32 -> Wp bf16; two src offsets per K=32 step:
// Wp[((k2*4+q)*COUT+n)*8+j] = W[2*k2+(q>>1)][(q&1)*8+j][n] (zero past Ksrc)
__global__ void pack_w16(const float* __restrict__ W, unsigned short* __restrict__ Wp,
                         int K2, int COUT, int Ksrc) {
    int t = blockIdx.x * blockDim.x + threadIdx.x;
    if (t >= K2 * 4 * COUT * 8) return;
    int j = t & 7;
    int r = t >> 3;
    int n = r % COUT; r /= COUT;
    int q = r & 3;
    int k2 = r >> 2;
    int ks = 2 * k2 + (q >> 1);
    int cin = (q & 1) * 8 + j;
    float v = (ks < Ksrc) ? W[(ks * 16 + cin) * COUT + n] : 0.f;
    Wp[t] = f2b(v);
}

// first conv: C_IN=1 -> 16, K=27, relu; writes f32 (cached out) + bf16 copy
__global__ __launch_bounds__(TPB) void conv_first_k(
    const float* __restrict__ xin, const float* __restrict__ W,
    const float* __restrict__ b, const int* __restrict__ tab, long long rowcap,
    int n0, float* __restrict__ outf, unsigned short* __restrict__ outb) {
    int j = blockIdx.x * blockDim.x + threadIdx.x;
    if (j >= n0) return;
    float acc[16];
#pragma unroll
    for (int c = 0; c < 16; ++c) acc[c] = b[c];
#pragma unroll
    for (int k = 0; k < 27; ++k) {
        int idx = tab[(long long)k * rowcap + j];
        int cidx = idx < n0 ? idx : 0;
        float v = xin[cidx];
        v = idx < n0 ? v : 0.f;
        const float* Wk = W + k * 16;
#pragma unroll
        for (int c = 0; c < 16; ++c) acc[c] = fmaf(v, Wk[c], acc[c]);
    }
    float* orow = outf + (long long)j * 16;
    unsigned short* brow = outb + (long long)j * 16;
#pragma unroll
    for (int c = 0; c < 16; ++c) {
        float v = fmaxf(acc[c], 0.f);
        orow[c] = v;
        brow[c] = f2b(v);
    }
}

// MFMA conv, M=64 per wave. CIN=32: one offset per K=32 step (coff=q*8).
// CIN=16: two offsets per step (ks=2s+(q>>1), coff=(q&1)*8).
template <int CIN, int COUT, int STEPS, bool RELU, bool RES, bool WF32, bool WB16>
__global__ __launch_bounds__(TPB, 4) void conv_mfma(
    const unsigned short* __restrict__ xb,   // (n_in+1, CIN) bf16, pad row zero
    const unsigned short* __restrict__ Wp,   // packed STEPS*4*COUT*8 bf16
    const float* __restrict__ bias,
    const int* __restrict__ tab, long long rowcap, int n_out,
    const unsigned short* __restrict__ resb,
    float* __restrict__ outf, unsigned short* __restrict__ outb) {
    constexpr int NT = COUT / 16;
    int wid = (blockIdx.x * (int)blockDim.x + (int)threadIdx.x) >> 6;
    int lane = threadIdx.x & 63;
    int m = lane & 15, q = lane >> 4;
    long long j0 = (long long)wid * 64;
    if (j0 >= n_out) return;
    floatx4 acc[4][NT];
#pragma unroll
    for (int t = 0; t < 4; ++t)
#pragma unroll
        for (int nt = 0; nt < NT; ++nt) acc[t][nt] = floatx4{0.f, 0.f, 0.f, 0.f};
#pragma unroll
    for (int s = 0; s < STEPS; ++s) {
        int ks, coff;
        if (CIN == 32) { ks = s; coff = q * 8; }
        else { ks = 2 * s + (q >> 1); coff = (q & 1) * 8; }
        const int* trow = tab + (long long)ks * rowcap + j0 + m;
        int idx[4];
#pragma unroll
        for (int t = 0; t < 4; ++t) idx[t] = trow[16 * t];
        short8 b0 = *(const short8*)(Wp + (((s * 4 + q) * COUT) + m) * 8);
        short8 b1;
        if (NT == 2) b1 = *(const short8*)(Wp + (((s * 4 + q) * COUT) + 16 + m) * 8);
#pragma unroll
        for (int t = 0; t < 4; ++t) {
            short8 a = *(const short8*)(xb + (long long)idx[t] * CIN + coff);
            acc[t][0] = __builtin_amdgcn_mfma_f32_16x16x32_bf16(a, b0, acc[t][0], 0, 0, 0);
            if (NT == 2)
                acc[t][1] = __builtin_amdgcn_mfma_f32_16x16x32_bf16(a, b1, acc[t][1], 0, 0, 0);
        }
    }
    float bs[2];
    bs[0] = bias[m];
    if (NT == 2) bs[1] = bias[16 + m];
#pragma unroll
    for (int t = 0; t < 4; ++t) {
#pragma unroll
        for (int u = 0; u < 4; ++u) {
            long long r = j0 + 16 * t + q * 4 + u;   // C/D: row=(lane>>4)*4+reg
            if (r < n_out) {
#pragma unroll
                for (int nt = 0; nt < NT; ++nt) {
                    float v = acc[t][nt][u] + bs[nt];
                    if (RES) v += b2f(resb[r * COUT + nt * 16 + m]);
                    if (RELU) v = fmaxf(v, 0.f);
                    if (WF32) outf[r * COUT + nt * 16 + m] = v;
                    if (WB16) outb[r * COUT + nt * 16 + m] = f2b(v);
                }
            }
        }
    }
}

static inline unsigned nblk(long long n, int b) { return (unsigned)((n + b - 1) / b); }
static inline size_t align64(size_t x) { return (x + 63) & ~(size_t)63; }

extern "C" void kernel_launch(void* const* d_in, const int* in_sizes, int n_in_cnt,
                              void* d_out, int out_size, void* d_ws, size_t ws_size,
                              hipStream_t stream) {
    const float* in_feats = (const float*)d_in[0];
    const float* W_first = (const float*)d_in[1];
    const float* b_first = (const float*)d_in[2];
    const float* W_pre   = (const float*)d_in[3];
    const float* b_pre   = (const float*)d_in[4];
    const float* W_down  = (const float*)d_in[5];
    const float* b_down  = (const float*)d_in[6];
    const float* W_r0    = (const float*)d_in[7];
    const float* b_r0    = (const float*)d_in[8];
    const float* W_r1    = (const float*)d_in[9];
    const float* b_r1    = (const float*)d_in[10];
    const float* W_fin   = (const float*)d_in[11];
    const float* b_fin   = (const float*)d_in[12];
    const int* km0_in  = (const int*)d_in[13];
    const int* km0_out = (const int*)d_in[14];
    const int* kmd_in  = (const int*)d_in[15];
    const int* kmd_out = (const int*)d_in[16];
    const int* km1_in  = (const int*)d_in[17];
    const int* km1_out = (const int*)d_in[18];

    const int n0 = in_sizes[0];
    const int n1 = (out_size - 16 * n0) / 32;
    const long long P0 = in_sizes[13] / 27;
    const long long Pd = in_sizes[15] / 8;
    const long long P1 = in_sizes[17] / 27;

    // rowcap: multiple of 64 covering n+1 (pad slot) and the last wave's rows
    const long long rc0 = ((n0 + 64) / 64) * 64;
    const long long rc1 = ((n1 + 64) / 64) * 64;

    float* out_lo = (float*)d_out;                 // (n1,32)
    float* cached = out_lo + (size_t)n1 * 32;      // (n0,16) f32

    char* base = (char*)d_ws;
    size_t off = 0;
    auto alloc = [&](size_t bytes) { void* p = base + off; off = align64(off + bytes); return p; };
    int* t0 = (int*)alloc(sizeof(int) * 28 * rc0);     // 27 offsets + zero row 27
    int* t1 = (int*)alloc(sizeof(int) * 27 * rc1);
    int* td = (int*)alloc(sizeof(int) * 8 * rc1);
    unsigned short* c0b   = (unsigned short*)alloc(sizeof(short) * 16 * (n0 + 1));
    unsigned short* x0pre = (unsigned short*)alloc(sizeof(short) * 16 * (n0 + 1));
    unsigned short* x1a   = (unsigned short*)alloc(sizeof(short) * 32 * (n1 + 1));
    unsigned short* x1b   = (unsigned short*)alloc(sizeof(short) * 32 * (n1 + 1));
    unsigned short* x1c   = (unsigned short*)alloc(sizeof(short) * 32 * (n1 + 1));
    unsigned short* wp_pre  = (unsigned short*)alloc(sizeof(short) * 14 * 4 * 16 * 8);
    unsigned short* wp_down = (unsigned short*)alloc(sizeof(short) * 4 * 4 * 32 * 8);
    unsigned short* wp_r0   = (unsigned short*)alloc(sizeof(short) * 27 * 1024);
    unsigned short* wp_r1   = (unsigned short*)alloc(sizeof(short) * 27 * 1024);
    unsigned short* wp_fin  = (unsigned short*)alloc(sizeof(short) * 27 * 1024);
    (void)ws_size; (void)n_in_cnt;

    // tables (lengths are multiples of 4: rc is a multiple of 64)
    fill_i32v<<<nblk(28 * rc0 / 4, TPB), TPB, 0, stream>>>(t0, 28 * rc0 / 4, n0);
    fill_i32v<<<nblk(27 * rc1 / 4, TPB), TPB, 0, stream>>>(t1, 27 * rc1 / 4, n1);
    fill_i32v<<<nblk(8 * rc1 / 4, TPB), TPB, 0, stream>>>(td, 8 * rc1 / 4, n0);
    scatter_tab<<<nblk(27 * P0, TPB), TPB, 0, stream>>>(km0_in, km0_out, t0, rc0, P0, 27 * P0);
    scatter_tab<<<nblk(27 * P1, TPB), TPB, 0, stream>>>(km1_in, km1_out, t1, rc1, P1, 27 * P1);
    scatter_tab<<<nblk(8 * Pd, TPB), TPB, 0, stream>>>(kmd_in, kmd_out, td, rc1, Pd, 8 * Pd);

    // weight packing + pad rows
    pack_w16<<<nblk(14 * 4 * 16 * 8, TPB), TPB, 0, stream>>>(W_pre, wp_pre, 14, 16, 27);
    pack_w16<<<nblk(4 * 4 * 32 * 8, TPB), TPB, 0, stream>>>(W_down, wp_down, 4, 32, 8);
    pack_w32<<<nblk(27 * 1024, TPB), TPB, 0, stream>>>(W_r0, wp_r0, 27);
    pack_w32<<<nblk(27 * 1024, TPB), TPB, 0, stream>>>(W_r1, wp_r1, 27);
    pack_w32<<<nblk(27 * 1024, TPB), TPB, 0, stream>>>(W_fin, wp_fin, 27);
    zero_pads<<<1, 160, 0, stream>>>(c0b + (size_t)n0 * 16, x0pre + (size_t)n0 * 16,
                                     x1a + (size_t)n1 * 32, x1b + (size_t)n1 * 32,
                                     x1c + (size_t)n1 * 32);

    // first: 1 -> 16, relu -> cached (f32) + c0b (bf16)
    conv_first_k<<<nblk(n0, TPB), TPB, 0, stream>>>(in_feats, W_first, b_first, t0, rc0,
                                                    n0, cached, c0b);
    const long long th0 = (long long)nblk(n0, 64) * 64;  // one wave per 64 rows
    const long long th1 = (long long)nblk(n1, 64) * 64;
    // pre: 16 -> 16 relu (bf16 out)
    conv_mfma<16, 16, 14, true, false, false, true><<<nblk(th0, TPB), TPB, 0, stream>>>(
        c0b, wp_pre, b_pre, t0, rc0, n0, nullptr, nullptr, x0pre);
    // down: 16 -> 32 relu
    conv_mfma<16, 32, 4, true, false, false, true><<<nblk(th1, TPB), TPB, 0, stream>>>(
        x0pre, wp_down, b_down, td, rc1, n1, nullptr, nullptr, x1a);
    // r0: 32 -> 32 relu
    conv_mfma<32, 32, 27, true, false, false, true><<<nblk(th1, TPB), TPB, 0, stream>>>(
        x1a, wp_r0, b_r0, t1, rc1, n1, nullptr, nullptr, x1b);
    // r1: 32 -> 32 + residual x1a, no relu
    conv_mfma<32, 32, 27, false, true, false, true><<<nblk(th1, TPB), TPB, 0, stream>>>(
        x1b, wp_r1, b_r1, t1, rc1, n1, x1a, nullptr, x1c);
    // fin: 32 -> 32 -> d_out (f32)
    conv_mfma<32, 32, 27, false, false, true, false><<<nblk(th1, TPB), TPB, 0, stream>>>(
        x1c, wp_fin, b_fin, t1, rc1, n1, nullptr, out_lo, nullptr);
}

// Round 4
// 514.271 us; speedup vs baseline: 1.9784x; 1.0112x over previous
//
#include <hip/hip_runtime.h>

// Sparse-conv encoder, bf16-MFMA implicit-GEMM, M=64 per wave, TPB=128,
// explicit 2-deep idx / 1-deep gather software pipeline.
// tab[k][j] = in_idx; tables are memset to 0xFF and scatter-filled; convs
// clamp indices unsigned -> pad row n_in (zeroed) so unwritten slots are safe.

#define TPB 256      // for small utility kernels
#define TPC 128      // for MFMA convs (2 waves/block -> grid-limited occupancy fix)

typedef __attribute__((ext_vector_type(8))) short short8;
typedef __attribute__((ext_vector_type(4))) float floatx4;

static __device__ __forceinline__ unsigned short f2b(float f) {
    union { float f; unsigned u; } v; v.f = f;
    unsigned r = v.u + 0x7fffu + ((v.u >> 16) & 1u);   // RNE
    return (unsigned short)(r >> 16);
}
static __device__ __forceinline__ float b2f(unsigned short h) {
    union { unsigned u; float f; } v; v.u = ((unsigned)h) << 16;
    return v.f;
}

__global__ void scatter_tab(const int* __restrict__ km_in,
                            const int* __restrict__ km_out,
                            int* __restrict__ tab, long long rowcap, long long P,
                            long long total) {
    long long t = (long long)blockIdx.x * blockDim.x + threadIdx.x;
    if (t >= total) return;
    long long k = t / P;
    int o = km_out[t];               // pad -> n_out slot (inside rowcap)
    tab[k * rowcap + o] = km_in[t];
}

// zero the pad rows of the 5 bf16 feature buffers (ws is poisoned)
__global__ void zero_pads(unsigned short* a, unsigned short* b, unsigned short* c,
                          unsigned short* d, unsigned short* e) {
    int t = threadIdx.x;             // 160 threads
    if (t < 16) a[t] = 0;
    else if (t < 32) b[t - 16] = 0;
    else if (t < 64) c[t - 32] = 0;
    else if (t < 96) d[t - 64] = 0;
    else if (t < 128) e[t - 96] = 0;
}

// pack W (K,32,COUT=32) f32 -> Wp bf16 at [((k*4+q)*32+n)*8+j] = W[k][q*8+j][n]
__global__ void pack_w32(const float* __restrict__ W, unsigned short* __restrict__ Wp,
                         int K) {
    int t = blockIdx.x * blockDim.x + threadIdx.x;
    if (t >= K * 1024) return;
    int j = t & 7, n = (t >> 3) & 31, q = (t >> 8) & 3, k = t >> 10;
    Wp[t] = f2b(W[(k * 32 + q * 8 + j) * 32 + n]);
}

// pack W (Ksrc,16,COUT) f32 -> Wp bf16; two src offsets per K=32 step:
// Wp[((k2*4+q)*COUT+n)*8+j] = W[2*k2+(q>>1)][(q&1)*8+j][n] (zero past Ksrc)
__global__ void pack_w16(const float* __restrict__ W, unsigned short* __restrict__ Wp,
                         int K2, int COUT, int Ksrc) {
    int t = blockIdx.x * blockDim.x + threadIdx.x;
    if (t >= K2 * 4 * COUT * 8) return;
    int j = t & 7;
    int r = t >> 3;
    int n = r % COUT; r /= COUT;
    int q = r & 3;
    int k2 = r >> 2;
    int ks = 2 * k2 + (q >> 1);
    int cin = (q & 1) * 8 + j;
    float v = (ks < Ksrc) ? W[(ks * 16 + cin) * COUT + n] : 0.f;
    Wp[t] = f2b(v);
}

// first conv: C_IN=1 -> 16, K=27, relu; writes f32 (cached out) + bf16 copy
__global__ __launch_bounds__(TPB) void conv_first_k(
    const float* __restrict__ xin, const float* __restrict__ W,
    const float* __restrict__ b, const int* __restrict__ tab, long long rowcap,
    int n0, float* __restrict__ outf, unsigned short* __restrict__ outb) {
    int j = blockIdx.x * blockDim.x + threadIdx.x;
    if (j >= n0) return;
    float acc[16];
#pragma unroll
    for (int c = 0; c < 16; ++c) acc[c] = b[c];
#pragma unroll
    for (int k = 0; k < 27; ++k) {
        int idx = tab[(long long)k * rowcap + j];
        bool ok = (unsigned)idx < (unsigned)n0;
        int cidx = ok ? idx : 0;
        float v = xin[cidx];
        v = ok ? v : 0.f;
        const float* Wk = W + k * 16;
#pragma unroll
        for (int c = 0; c < 16; ++c) acc[c] = fmaf(v, Wk[c], acc[c]);
    }
    float* orow = outf + (long long)j * 16;
    unsigned short* brow = outb + (long long)j * 16;
#pragma unroll
    for (int c = 0; c < 16; ++c) {
        float v = fmaxf(acc[c], 0.f);
        orow[c] = v;
        brow[c] = f2b(v);
    }
}

// MFMA conv, M=64 per wave, software-pipelined (idx +2, gather +1).
// CIN=32: one offset per K=32 step (coff=q*8).
// CIN=16: two offsets per step (ks=2s+(q>>1), coff=(q&1)*8).
template <int CIN, int COUT, int STEPS, bool RELU, bool RES, bool WF32, bool WB16>
__global__ __launch_bounds__(TPC) void conv_mfma(
    const unsigned short* __restrict__ xb,   // (n_in+1, CIN) bf16, pad row zero
    const unsigned short* __restrict__ Wp,   // packed STEPS*4*COUT*8 bf16
    const float* __restrict__ bias,
    const int* __restrict__ tab, long long rowcap, int n_in, int n_out,
    const unsigned short* __restrict__ resb,
    float* __restrict__ outf, unsigned short* __restrict__ outb) {
    constexpr int NT = COUT / 16;
    int wid = (blockIdx.x * (int)blockDim.x + (int)threadIdx.x) >> 6;
    int lane = threadIdx.x & 63;
    int m = lane & 15, q = lane >> 4;
    long long j0 = (long long)wid * 64;
    if (j0 >= n_out) return;

    floatx4 acc[4][NT];
#pragma unroll
    for (int t = 0; t < 4; ++t)
#pragma unroll
        for (int nt = 0; nt < NT; ++nt) acc[t][nt] = floatx4{0.f, 0.f, 0.f, 0.f};

    const int coff = (CIN == 32) ? q * 8 : (q & 1) * 8;

    auto load_idx = [&](int s, int (&dst)[4]) {
        int ks = (CIN == 32) ? s : 2 * s + (q >> 1);
        const int* trow = tab + (long long)ks * rowcap + j0 + m;
#pragma unroll
        for (int t = 0; t < 4; ++t) {
            int v = trow[16 * t];
            dst[t] = ((unsigned)v < (unsigned)n_in) ? v : n_in;  // pad -> zero row
        }
    };
    auto gather = [&](const int (&src)[4], short8 (&dst)[4]) {
#pragma unroll
        for (int t = 0; t < 4; ++t)
            dst[t] = *(const short8*)(xb + (long long)src[t] * CIN + coff);
    };

    int idxB[4];
    short8 aCur[4];
    {
        int idxA[4];
        load_idx(0, idxA);
        if (STEPS > 1) load_idx(1, idxB);
        gather(idxA, aCur);
    }
#pragma unroll
    for (int s = 0; s < STEPS; ++s) {
        int idxN[4];
        short8 aN[4];
        if (s + 2 < STEPS) load_idx(s + 2, idxN);
        if (s + 1 < STEPS) gather(idxB, aN);
        short8 b0 = *(const short8*)(Wp + (((s * 4 + q) * COUT) + m) * 8);
        short8 b1;
        if (NT == 2) b1 = *(const short8*)(Wp + (((s * 4 + q) * COUT) + 16 + m) * 8);
#pragma unroll
        for (int t = 0; t < 4; ++t) {
            acc[t][0] = __builtin_amdgcn_mfma_f32_16x16x32_bf16(aCur[t], b0, acc[t][0], 0, 0, 0);
            if (NT == 2)
                acc[t][1] = __builtin_amdgcn_mfma_f32_16x16x32_bf16(aCur[t], b1, acc[t][1], 0, 0, 0);
        }
#pragma unroll
        for (int t = 0; t < 4; ++t) {
            if (s + 1 < STEPS) aCur[t] = aN[t];
            if (s + 2 < STEPS) idxB[t] = idxN[t];
        }
    }

    float bs[2];
    bs[0] = bias[m];
    if (NT == 2) bs[1] = bias[16 + m];
#pragma unroll
    for (int t = 0; t < 4; ++t) {
#pragma unroll
        for (int u = 0; u < 4; ++u) {
            long long r = j0 + 16 * t + q * 4 + u;   // C/D: row=(lane>>4)*4+reg
            if (r < n_out) {
#pragma unroll
                for (int nt = 0; nt < NT; ++nt) {
                    float v = acc[t][nt][u] + bs[nt];
                    if (RES) v += b2f(resb[r * COUT + nt * 16 + m]);
                    if (RELU) v = fmaxf(v, 0.f);
                    if (WF32) outf[r * COUT + nt * 16 + m] = v;
                    if (WB16) outb[r * COUT + nt * 16 + m] = f2b(v);
                }
            }
        }
    }
}

static inline unsigned nblk(long long n, int b) { return (unsigned)((n + b - 1) / b); }
static inline size_t align64(size_t x) { return (x + 63) & ~(size_t)63; }

extern "C" void kernel_launch(void* const* d_in, const int* in_sizes, int n_in_cnt,
                              void* d_out, int out_size, void* d_ws, size_t ws_size,
                              hipStream_t stream) {
    const float* in_feats = (const float*)d_in[0];
    const float* W_first = (const float*)d_in[1];
    const float* b_first = (const float*)d_in[2];
    const float* W_pre   = (const float*)d_in[3];
    const float* b_pre   = (const float*)d_in[4];
    const float* W_down  = (const float*)d_in[5];
    const float* b_down  = (const float*)d_in[6];
    const float* W_r0    = (const float*)d_in[7];
    const float* b_r0    = (const float*)d_in[8];
    const float* W_r1    = (const float*)d_in[9];
    const float* b_r1    = (const float*)d_in[10];
    const float* W_fin   = (const float*)d_in[11];
    const float* b_fin   = (const float*)d_in[12];
    const int* km0_in  = (const int*)d_in[13];
    const int* km0_out = (const int*)d_in[14];
    const int* kmd_in  = (const int*)d_in[15];
    const int* kmd_out = (const int*)d_in[16];
    const int* km1_in  = (const int*)d_in[17];
    const int* km1_out = (const int*)d_in[18];

    const int n0 = in_sizes[0];
    const int n1 = (out_size - 16 * n0) / 32;
    const long long P0 = in_sizes[13] / 27;
    const long long Pd = in_sizes[15] / 8;
    const long long P1 = in_sizes[17] / 27;

    // rowcap: multiple of 64 covering n+1 (pad slot) and the last wave's rows
    const long long rc0 = ((n0 + 64) / 64) * 64;
    const long long rc1 = ((n1 + 64) / 64) * 64;

    float* out_lo = (float*)d_out;                 // (n1,32)
    float* cached = out_lo + (size_t)n1 * 32;      // (n0,16) f32

    char* base = (char*)d_ws;
    size_t off = 0;
    auto alloc = [&](size_t bytes) { void* p = base + off; off = align64(off + bytes); return p; };
    int* t0 = (int*)alloc(sizeof(int) * 28 * rc0);     // 27 offsets + zero row for ks=27
    int* t1 = (int*)alloc(sizeof(int) * 27 * rc1);
    int* td = (int*)alloc(sizeof(int) * 8 * rc1);
    unsigned short* c0b   = (unsigned short*)alloc(sizeof(short) * 16 * (n0 + 1));
    unsigned short* x0pre = (unsigned short*)alloc(sizeof(short) * 16 * (n0 + 1));
    unsigned short* x1a   = (unsigned short*)alloc(sizeof(short) * 32 * (n1 + 1));
    unsigned short* x1b   = (unsigned short*)alloc(sizeof(short) * 32 * (n1 + 1));
    unsigned short* x1c   = (unsigned short*)alloc(sizeof(short) * 32 * (n1 + 1));
    unsigned short* wp_pre  = (unsigned short*)alloc(sizeof(short) * 14 * 4 * 16 * 8);
    unsigned short* wp_down = (unsigned short*)alloc(sizeof(short) * 4 * 4 * 32 * 8);
    unsigned short* wp_r0   = (unsigned short*)alloc(sizeof(short) * 27 * 1024);
    unsigned short* wp_r1   = (unsigned short*)alloc(sizeof(short) * 27 * 1024);
    unsigned short* wp_fin  = (unsigned short*)alloc(sizeof(short) * 27 * 1024);
    (void)ws_size; (void)n_in_cnt;

    // tables: 0xFF fill (=> unsigned-huge => pad) + scatter valid entries
    hipMemsetAsync(t0, 0xFF, sizeof(int) * 28 * rc0, stream);
    hipMemsetAsync(t1, 0xFF, sizeof(int) * 27 * rc1, stream);
    hipMemsetAsync(td, 0xFF, sizeof(int) * 8 * rc1, stream);
    scatter_tab<<<nblk(27 * P0, TPB), TPB, 0, stream>>>(km0_in, km0_out, t0, rc0, P0, 27 * P0);
    scatter_tab<<<nblk(27 * P1, TPB), TPB, 0, stream>>>(km1_in, km1_out, t1, rc1, P1, 27 * P1);
    scatter_tab<<<nblk(8 * Pd, TPB), TPB, 0, stream>>>(kmd_in, kmd_out, td, rc1, Pd, 8 * Pd);

    // weight packing + pad rows
    pack_w16<<<nblk(14 * 4 * 16 * 8, TPB), TPB, 0, stream>>>(W_pre, wp_pre, 14, 16, 27);
    pack_w16<<<nblk(4 * 4 * 32 * 8, TPB), TPB, 0, stream>>>(W_down, wp_down, 4, 32, 8);
    pack_w32<<<nblk(27 * 1024, TPB), TPB, 0, stream>>>(W_r0, wp_r0, 27);
    pack_w32<<<nblk(27 * 1024, TPB), TPB, 0, stream>>>(W_r1, wp_r1, 27);
    pack_w32<<<nblk(27 * 1024, TPB), TPB, 0, stream>>>(W_fin, wp_fin, 27);
    zero_pads<<<1, 160, 0, stream>>>(c0b + (size_t)n0 * 16, x0pre + (size_t)n0 * 16,
                                     x1a + (size_t)n1 * 32, x1b + (size_t)n1 * 32,
                                     x1c + (size_t)n1 * 32);

    // first: 1 -> 16, relu -> cached (f32) + c0b (bf16)
    conv_first_k<<<nblk(n0, TPB), TPB, 0, stream>>>(in_feats, W_first, b_first, t0, rc0,
                                                    n0, cached, c0b);
    const long long w0 = nblk(n0, 64), w1 = nblk(n1, 64);   // waves
    // pre: 16 -> 16 relu (bf16 out)
    conv_mfma<16, 16, 14, true, false, false, true><<<nblk(w0 * 64, TPC), TPC, 0, stream>>>(
        c0b, wp_pre, b_pre, t0, rc0, n0, n0, nullptr, nullptr, x0pre);
    // down: 16 -> 32 relu
    conv_mfma<16, 32, 4, true, false, false, true><<<nblk(w1 * 64, TPC), TPC, 0, stream>>>(
        x0pre, wp_down, b_down, td, rc1, n0, n1, nullptr, nullptr, x1a);
    // r0: 32 -> 32 relu
    conv_mfma<32, 32, 27, true, false, false, true><<<nblk(w1 * 64, TPC), TPC, 0, stream>>>(
        x1a, wp_r0, b_r0, t1, rc1, n1, n1, nullptr, nullptr, x1b);
    // r1: 32 -> 32 + residual x1a, no relu
    conv_mfma<32, 32, 27, false, true, false, true><<<nblk(w1 * 64, TPC), TPC, 0, stream>>>(
        x1b, wp_r1, b_r1, t1, rc1, n1, n1, x1a, nullptr, x1c);
    // fin: 32 -> 32 -> d_out (f32)
    conv_mfma<32, 32, 27, false, false, true, false><<<nblk(w1 * 64, TPC), TPC, 0, stream>>>(
        x1c, wp_fin, b_fin, t1, rc1, n1, n1, nullptr, out_lo, nullptr);
}